// Round 12
// baseline (308.350 us; speedup 1.0000x reference)
//
#include <hip/hip_runtime.h>

#define Bd 4
#define Ld 512
#define DMd 1024
#define Hd 16
#define DKd 64
#define DRd 64
#define DFd 4096
#define LDN 4096

typedef unsigned short ushort_t;
typedef short bf16x8 __attribute__((ext_vector_type(8)));
typedef float f32x4 __attribute__((ext_vector_type(4)));
typedef unsigned short ushort8 __attribute__((ext_vector_type(8)));

__device__ __forceinline__ float bf2f(ushort_t u) {
    return __uint_as_float(((unsigned int)u) << 16);
}
__device__ __forceinline__ ushort_t f2bf(float x) {
    unsigned int u = __float_as_uint(x);
    unsigned int r = (u + 0x7fffu + ((u >> 16) & 1u)) >> 16;
    return (ushort_t)r;
}
// round-half-up bf16 pair pack: 2 adds + 1 v_perm per 2 elements
__device__ __forceinline__ unsigned int pack2(float a, float b) {
    unsigned int ua = __float_as_uint(a) + 0x8000u;
    unsigned int ub = __float_as_uint(b) + 0x8000u;
    return __builtin_amdgcn_perm(ub, ua, 0x07060302u);
}
__device__ __forceinline__ bf16x8 cvt8p(float4 a, float4 b) {
    union { unsigned int u[4]; bf16x8 v; } r;
    r.u[0] = pack2(a.x, a.y);
    r.u[1] = pack2(a.z, a.w);
    r.u[2] = pack2(b.x, b.y);
    r.u[3] = pack2(b.z, b.w);
    return r.v;
}
__device__ __forceinline__ ushort_t f2bf_hu(float x) {
    return (ushort_t)((__float_as_uint(x) + 0x8000u) >> 16);
}

typedef __attribute__((address_space(3))) void as3_void;
typedef const __attribute__((address_space(1))) void as1_cvoid;
__device__ __forceinline__ void gld_lds16(const ushort_t* g, ushort_t* l) {
    __builtin_amdgcn_global_load_lds((as1_cvoid*)g, (as3_void*)l, 16, 0, 0);
}

// ---------------------------------------------------------------- LayerNorm (fp32 in, bf16 out)
__global__ __launch_bounds__(256) void ln_kernel(const float* __restrict__ x,
                                                 const float* __restrict__ g,
                                                 const float* __restrict__ bta,
                                                 ushort_t* __restrict__ out) {
    __shared__ float red[4];
    int row = blockIdx.x;
    int t = threadIdx.x;
    const float* xr = x + (size_t)row * DMd;
    float4 xv = *(const float4*)(xr + t * 4);
    float s = xv.x + xv.y + xv.z + xv.w;
    #pragma unroll
    for (int off = 32; off; off >>= 1) s += __shfl_down(s, off, 64);
    if ((t & 63) == 0) red[t >> 6] = s;
    __syncthreads();
    float mean = (red[0] + red[1] + red[2] + red[3]) * (1.0f / DMd);
    __syncthreads();
    float dx = xv.x - mean, dy = xv.y - mean, dz = xv.z - mean, dw = xv.w - mean;
    float vs = dx * dx + dy * dy + dz * dz + dw * dw;
    #pragma unroll
    for (int off = 32; off; off >>= 1) vs += __shfl_down(vs, off, 64);
    if ((t & 63) == 0) red[t >> 6] = vs;
    __syncthreads();
    float var = (red[0] + red[1] + red[2] + red[3]) * (1.0f / DMd);
    float inv = rsqrtf(var + 1e-6f);
    float4 gv = *(const float4*)(g + t * 4);
    float4 bv = *(const float4*)(bta + t * 4);
    ushort4 o;
    o.x = f2bf(dx * inv * gv.x + bv.x);
    o.y = f2bf(dy * inv * gv.y + bv.y);
    o.z = f2bf(dz * inv * gv.z + bv.z);
    o.w = f2bf(dw * inv * gv.w + bv.w);
    *(ushort4*)(out + (size_t)row * DMd + t * 4) = o;
}

// -------------------------------------------------- transpose+cast: W[K][N] f32 -> Wt[N][K] bf16
__global__ __launch_bounds__(256) void transpose_cast(const float* __restrict__ W,
                                                      ushort_t* __restrict__ Wt,
                                                      int K, int N) {
    __shared__ float tile[32][33];
    int t = threadIdx.x;
    int n0 = blockIdx.x * 32, k0 = blockIdx.y * 32;
    int r = t >> 3, c4 = (t & 7) * 4;
    float4 w = *(const float4*)&W[(size_t)(k0 + r) * N + n0 + c4];
    tile[r][c4 + 0] = w.x; tile[r][c4 + 1] = w.y;
    tile[r][c4 + 2] = w.z; tile[r][c4 + 3] = w.w;
    __syncthreads();
    int n = t >> 3, k4 = (t & 7) * 4;
    ushort4 o;
    o.x = f2bf(tile[k4 + 0][n]); o.y = f2bf(tile[k4 + 1][n]);
    o.z = f2bf(tile[k4 + 2][n]); o.w = f2bf(tile[k4 + 3][n]);
    *(ushort4*)&Wt[(size_t)(n0 + n) * K + k0 + k4] = o;
}

// ---------------------------- 3 stacked 1024x1024 transposes (Wq/Wk/Wv) in one launch
__global__ __launch_bounds__(256) void transpose_cast3(const float* __restrict__ W0,
                                                       const float* __restrict__ W1p,
                                                       const float* __restrict__ W2p,
                                                       ushort_t* __restrict__ Wt) {
    __shared__ float tile[32][33];
    int z = blockIdx.z;
    const float* W = (z == 0) ? W0 : (z == 1 ? W1p : W2p);
    ushort_t* dst = Wt + (size_t)z * 1024 * 1024;
    int t = threadIdx.x;
    int n0 = blockIdx.x * 32, k0 = blockIdx.y * 32;
    int r = t >> 3, c4 = (t & 7) * 4;
    float4 w = *(const float4*)&W[(size_t)(k0 + r) * 1024 + n0 + c4];
    tile[r][c4 + 0] = w.x; tile[r][c4 + 1] = w.y;
    tile[r][c4 + 2] = w.z; tile[r][c4 + 3] = w.w;
    __syncthreads();
    int n = t >> 3, k4 = (t & 7) * 4;
    ushort4 o;
    o.x = f2bf(tile[k4 + 0][n]); o.y = f2bf(tile[k4 + 1][n]);
    o.z = f2bf(tile[k4 + 2][n]); o.w = f2bf(tile[k4 + 3][n]);
    *(ushort4*)&dst[(size_t)(n0 + n) * 1024 + k0 + k4] = o;
}

// ---------------- Wqrt[3072 + h*64+r][k] = 0.125 * sum_d Wr[r][d] * Wq[k][h*64+d]
__global__ __launch_bounds__(256) void wqr_kernel(const float* __restrict__ Wq,
                                                  const float* __restrict__ Wr,
                                                  ushort_t* __restrict__ Wqkvt) {
    __shared__ float wr_s[64 * 64];
    __shared__ float wq_s[64 * 68];
    int h = blockIdx.x >> 4, kc = blockIdx.x & 15;
    int t = threadIdx.x;
    #pragma unroll
    for (int i = 0; i < 4; i++) {
        int idx = t + i * 256;
        *(float4*)&wr_s[idx * 4] = *(const float4*)&Wr[idx * 4];
        int kk = idx >> 4, d4 = (idx & 15) * 4;
        *(float4*)&wq_s[kk * 68 + d4] =
            *(const float4*)&Wq[(size_t)(kc * 64 + kk) * 1024 + h * 64 + d4];
    }
    __syncthreads();
    int r = t >> 2, kq = t & 3;
    float acc[16] = {};
    for (int d = 0; d < 64; d++) {
        float wr = wr_s[r * 64 + d];
        #pragma unroll
        for (int i = 0; i < 16; i++) acc[i] += wr * wq_s[(kq * 16 + i) * 68 + d];
    }
    ushort8 o0, o1;
    #pragma unroll
    for (int i = 0; i < 8; i++) {
        o0[i] = f2bf(acc[i] * 0.125f);
        o1[i] = f2bf(acc[8 + i] * 0.125f);
    }
    ushort_t* dst = Wqkvt + ((size_t)(3072 + h * 64 + r)) * 1024 + kc * 64 + kq * 16;
    *(ushort8*)dst = o0;
    *(ushort8*)(dst + 8) = o1;
}

// ------------------ qkvb[0..3071] = bq|bk|bv ; qkvb[3072+h*64+r] = 0.125*sum_d bq[h*64+d]Wr[r][d]
__global__ __launch_bounds__(256) void catbias(const float* __restrict__ bq,
                                               const float* __restrict__ bk,
                                               const float* __restrict__ bv,
                                               const float* __restrict__ Wr,
                                               float* __restrict__ o) {
    int i = blockIdx.x * 256 + threadIdx.x;
    float v;
    if (i < 1024) v = bq[i];
    else if (i < 2048) v = bk[i - 1024];
    else if (i < 3072) v = bv[i - 2048];
    else {
        int j = i - 3072, h = j >> 6, r = j & 63;
        float a = 0.0f;
        for (int d = 0; d < 64; d++) a += bq[h * 64 + d] * Wr[r * 64 + d];
        v = a * 0.125f;
    }
    o[i] = v;
}

// ------------------------------------------------- bf16 MFMA GEMM + epilogue (2-phase dbuf)
template <int EPI, int OUTBF16, int BN_>
__global__ __launch_bounds__(256) void gemm_bf16(const ushort_t* __restrict__ A,
                                                 const ushort_t* __restrict__ Bt,
                                                 const float* __restrict__ bias,
                                                 const float* __restrict__ res,
                                                 void* __restrict__ Cout,
                                                 int M, int N, int K) {
    constexpr int NI = BN_ / 32;
    constexpr int NCB = BN_ / 32;
    __shared__ ushort_t A_s[2][128 * 64];
    __shared__ ushort_t B_s[2][BN_ * 64];
    int t = threadIdx.x, lane = t & 63, w = t >> 6;

    int nbx = gridDim.x;
    int flat = blockIdx.y * nbx + blockIdx.x;
    int cpx = (nbx * gridDim.y) >> 3;
    int swz = (flat & 7) * cpx + (flat >> 3);
    int bx = swz % nbx, by = swz / nbx;
    int row0 = by * 128, col0 = bx * BN_;

    int wm0 = (w >> 1) * 64;
    int wn0 = (w & 1) * (BN_ / 2);
    int srow = lane >> 3;
    int sp = lane & 7;
    int scol = (sp ^ srow) * 8;

    const ushort_t* Abase = A + (size_t)row0 * K + scol;
    const ushort_t* Bbase = Bt + (size_t)col0 * K + scol;

    f32x4 acc[4][NI] = {};
    int nt = K >> 6;

    #pragma unroll
    for (int i = 0; i < 4; i++) {
        int cc = w * 4 + i;
        gld_lds16(Abase + (size_t)(cc * 8 + srow) * K, &A_s[0][cc * 512]);
    }
    #pragma unroll
    for (int i = 0; i < NCB; i++) {
        int cc = w * NCB + i;
        gld_lds16(Bbase + (size_t)(cc * 8 + srow) * K, &B_s[0][cc * 512]);
    }
    __syncthreads();

    for (int kt = 0; kt < nt; kt++) {
        int cur = kt & 1;
        if (kt + 1 < nt) {
            int k0 = (kt + 1) << 6;
            #pragma unroll
            for (int i = 0; i < 4; i++) {
                int cc = w * 4 + i;
                gld_lds16(Abase + (size_t)(cc * 8 + srow) * K + k0, &A_s[cur ^ 1][cc * 512]);
            }
            #pragma unroll
            for (int i = 0; i < NCB; i++) {
                int cc = w * NCB + i;
                gld_lds16(Bbase + (size_t)(cc * 8 + srow) * K + k0, &B_s[cur ^ 1][cc * 512]);
            }
        }
        #pragma unroll
        for (int c = 0; c < 2; c++) {
            int q8 = c * 4 + (lane >> 4);
            bf16x8 af[4], bfr[NI];
            #pragma unroll
            for (int mi = 0; mi < 4; mi++) {
                int row = wm0 + mi * 16 + (lane & 15);
                af[mi] = *(bf16x8*)&A_s[cur][row * 64 + ((q8 ^ (row & 7)) * 8)];
            }
            #pragma unroll
            for (int ni = 0; ni < NI; ni++) {
                int row = wn0 + ni * 16 + (lane & 15);
                bfr[ni] = *(bf16x8*)&B_s[cur][row * 64 + ((q8 ^ (row & 7)) * 8)];
            }
            #pragma unroll
            for (int mi = 0; mi < 4; mi++)
                #pragma unroll
                for (int ni = 0; ni < NI; ni++)
                    acc[mi][ni] = __builtin_amdgcn_mfma_f32_16x16x32_bf16(af[mi], bfr[ni], acc[mi][ni], 0, 0, 0);
        }
        __syncthreads();
    }
    #pragma unroll
    for (int mi = 0; mi < 4; mi++) {
        #pragma unroll
        for (int ni = 0; ni < NI; ni++) {
            int col = col0 + wn0 + ni * 16 + (lane & 15);
            float bcol = bias[col];
            #pragma unroll
            for (int r = 0; r < 4; r++) {
                int row = row0 + wm0 + mi * 16 + (lane >> 4) * 4 + r;
                float v = acc[mi][ni][r] + bcol;
                if (EPI == 1) v += res[(size_t)row * N + col];
                if (EPI == 2) v = fmaxf(v, 0.0f);
                if (OUTBF16) ((ushort_t*)Cout)[(size_t)row * N + col] = f2bf(v);
                else         ((float*)Cout)[(size_t)row * N + col] = v;
            }
        }
    }
}

// ----------------------------------------- S1 = Q.K^T * 0.125 (bf16), batched per (b,h)
__global__ __launch_bounds__(256) void qk_gemm(const ushort_t* __restrict__ qkv,
                                               ushort_t* __restrict__ S1) {
    __shared__ ushort_t Q_s[128 * 64];
    __shared__ ushort_t K_s[128 * 64];
    int t = threadIdx.x, lane = t & 63, w = t >> 6;
    int qt = blockIdx.x & 3, kt = (blockIdx.x >> 2) & 3, bh = blockIdx.x >> 4;
    int b = bh >> 4, h = bh & 15;
    const ushort_t* Qb = qkv + (size_t)(b * 512 + qt * 128) * LDN + h * 64;
    const ushort_t* Kb = qkv + (size_t)(b * 512 + kt * 128) * LDN + 1024 + h * 64;
    #pragma unroll
    for (int i = 0; i < 4; i++) {
        int cc = w + 4 * i;
        int flat = cc * 64 + lane;
        int row = flat >> 3, p = flat & 7;
        int srcoff = ((p ^ (row & 7)) * 8);
        gld_lds16(Qb + (size_t)row * LDN + srcoff, &Q_s[cc * 512]);
        gld_lds16(Kb + (size_t)row * LDN + srcoff, &K_s[cc * 512]);
    }
    __syncthreads();
    int wm0 = (w >> 1) * 64, wn0 = (w & 1) * 64;
    f32x4 acc[4][4] = {};
    #pragma unroll
    for (int c = 0; c < 2; c++) {
        int q8 = c * 4 + (lane >> 4);
        bf16x8 af[4], bfr[4];
        #pragma unroll
        for (int mi = 0; mi < 4; mi++) {
            int row = wm0 + mi * 16 + (lane & 15);
            af[mi] = *(bf16x8*)&Q_s[row * 64 + ((q8 ^ (row & 7)) * 8)];
        }
        #pragma unroll
        for (int ni = 0; ni < 4; ni++) {
            int row = wn0 + ni * 16 + (lane & 15);
            bfr[ni] = *(bf16x8*)&K_s[row * 64 + ((q8 ^ (row & 7)) * 8)];
        }
        #pragma unroll
        for (int mi = 0; mi < 4; mi++)
            #pragma unroll
            for (int ni = 0; ni < 4; ni++)
                acc[mi][ni] = __builtin_amdgcn_mfma_f32_16x16x32_bf16(af[mi], bfr[ni], acc[mi][ni], 0, 0, 0);
    }
    #pragma unroll
    for (int mi = 0; mi < 4; mi++) {
        #pragma unroll
        for (int ni = 0; ni < 4; ni++) {
            #pragma unroll
            for (int r = 0; r < 4; r++) {
                int qrow = qt * 128 + wm0 + mi * 16 + (lane >> 4) * 4 + r;
                int kcol = kt * 128 + wn0 + ni * 16 + (lane & 15);
                S1[((size_t)(b * 512 + qrow) * 16 + h) * 512 + kcol] = f2bf(acc[mi][ni][r] * 0.125f);
            }
        }
    }
}

// ---------------------------------------------------- Vt[b][h][d][k] = V[b][k][h*64+d]
__global__ __launch_bounds__(256) void vt_kernel(const ushort_t* __restrict__ qkv,
                                                 ushort_t* __restrict__ Vt) {
    __shared__ float tile[64][65];
    int t = threadIdx.x;
    int bh = blockIdx.x, b = bh >> 4, h = bh & 15;
    int kt = blockIdx.y;
    const ushort_t* src = qkv + (size_t)b * 512 * LDN + 2048 + h * 64;
    ushort_t* dst = Vt + (size_t)bh * 64 * 512;
    #pragma unroll
    for (int i = 0; i < 2; i++) {
        int item = t + i * 256;
        int kk = item >> 3, d8 = (item & 7) * 8;
        ushort8 v = *(const ushort8*)(src + (size_t)(kt * 64 + kk) * LDN + d8);
        #pragma unroll
        for (int j = 0; j < 8; j++) tile[kk][d8 + j] = bf2f(v[j]);
    }
    __syncthreads();
    #pragma unroll
    for (int i = 0; i < 2; i++) {
        int item = t + i * 256;
        int d = item >> 3, kc = (item & 7) * 8;
        ushort8 o;
        #pragma unroll
        for (int j = 0; j < 8; j++) o[j] = f2bf(tile[kc + j][d]);
        *(ushort8*)(dst + (size_t)d * 512 + kt * 64 + kc) = o;
    }
}

// ------------ fused: scores = S1 + qr.r_k^T -> softmax -> A ; ctx2 = (A@r_v)@Wr + br
//              phase A: per-wave private LDS chunks, NO barriers in K loop, 2-deep reg prefetch
//              phase B: direct-global r_v B-fragments (barrier-free)
__global__ __launch_bounds__(256, 4) void scar_kernel(const ushort_t* __restrict__ qkv,
                                                      const float* __restrict__ r_k,
                                                      const float* __restrict__ r_v,
                                                      const float* __restrict__ Wr,
                                                      const float* __restrict__ br,
                                                      ushort_t* __restrict__ S1A,
                                                      float* __restrict__ ctx2) {
    __shared__ float red[4][16];
    __shared__ ushort_t A_lds[16 * 512];     // 16 KB, XOR-swizzled [h][k]
    __shared__ ushort_t st[4][2][16 * 64];   // 16 KB: per-wave dbuf chunks [16k][64d]
    __shared__ float ar_s[16][68];
    int t = threadIdx.x, lane = t & 63, w = t >> 6;
    int bq = blockIdx.x;
    const ushort_t* qr = qkv + (size_t)bq * LDN + 3072;
    const float* rk = r_k + (size_t)bq * 512 * 64;
    const float* rv = r_v + (size_t)bq * 512 * 64;
    ushort_t* s1 = S1A + (size_t)bq * 16 * 512;

    // A-fragments of qr (per-head 16x64)
    bf16x8 af0 = *(const bf16x8*)&qr[(lane & 15) * 64 + (lane >> 4) * 8];
    bf16x8 af1 = *(const bf16x8*)&qr[(lane & 15) * 64 + 32 + (lane >> 4) * 8];

    // ---- phase A: wave w owns k-rows [w*128, w*128+128) = 8 chunks of 16
    int kw = w * 128;
    int lr = lane >> 4;              // 0..3
    int lc = lane & 15;              // d-col group (d0 = lc*4)
    int dg = (lane >> 1) & 7;        // (lc*4)>>3
    int dlo = (lane & 1) * 4;        // (lc*4)&7
    const float* rkb = rk + (size_t)(kw + lr) * 64 + lc * 4;

    float4 ra[4], rb[4];
    #pragma unroll
    for (int i = 0; i < 4; i++) ra[i] = *(const float4*)(rkb + (size_t)(i * 4) * 64);
    #pragma unroll
    for (int i = 0; i < 4; i++) rb[i] = *(const float4*)(rkb + (size_t)(16 + i * 4) * 64);

    f32x4 acc[8] = {};
    #pragma unroll
    for (int c = 0; c < 8; c++) {
        ushort_t* sb = &st[w][c & 1][0];
        #pragma unroll
        for (int i = 0; i < 4; i++) {
            float4 v = (c & 1) ? rb[i] : ra[i];
            int kl = i * 4 + lr;
            ushort4 o;
            o.x = f2bf_hu(v.x); o.y = f2bf_hu(v.y);
            o.z = f2bf_hu(v.z); o.w = f2bf_hu(v.w);
            *(ushort4*)&sb[kl * 64 + ((dg ^ (kl & 7)) * 8) + dlo] = o;
        }
        if (c + 2 < 8) {
            #pragma unroll
            for (int i = 0; i < 4; i++) {
                float4 v = *(const float4*)(rkb + (size_t)((c + 2) * 16 + i * 4) * 64);
                if (c & 1) rb[i] = v; else ra[i] = v;
            }
        }
        #pragma unroll
        for (int hf = 0; hf < 2; hf++) {
            int u = lc * 64 + (((hf * 4 + lr) ^ (lc & 7)) * 8);
            bf16x8 bfr = *(bf16x8*)&sb[u];
            acc[c] = __builtin_amdgcn_mfma_f32_16x16x32_bf16(hf ? af1 : af0, bfr, acc[c], 0, 0, 0);
        }
    }

    // ---- softmax (k = kw + c*16 + lc, h = lr*4 + r)
    int hb = lr * 4;
    float vals[8][4];
    #pragma unroll
    for (int c = 0; c < 8; c++)
        #pragma unroll
        for (int r = 0; r < 4; r++)
            vals[c][r] = acc[c][r] + bf2f(s1[(hb + r) * 512 + kw + c * 16 + lc]);

    float m[4];
    #pragma unroll
    for (int r = 0; r < 4; r++) {
        m[r] = vals[0][r];
        #pragma unroll
        for (int c = 1; c < 8; c++) m[r] = fmaxf(m[r], vals[c][r]);
        #pragma unroll
        for (int msk = 1; msk < 16; msk <<= 1) m[r] = fmaxf(m[r], __shfl_xor(m[r], msk, 64));
    }
    if (lc == 0) {
        #pragma unroll
        for (int r = 0; r < 4; r++) red[w][hb + r] = m[r];
    }
    __syncthreads();
    float sum[4];
    #pragma unroll
    for (int r = 0; r < 4; r++) {
        float mg = fmaxf(fmaxf(red[0][hb + r], red[1][hb + r]),
                         fmaxf(red[2][hb + r], red[3][hb + r]));
        float s = 0.0f;
        #pragma unroll
        for (int c = 0; c < 8; c++) {
            float e = __expf(vals[c][r] - mg);
            vals[c][r] = e;
            s += e;
        }
        #pragma unroll
        for (int msk = 1; msk < 16; msk <<= 1) s += __shfl_xor(s, msk, 64);
        sum[r] = s;
    }
    __syncthreads();
    if (lc == 0) {
        #pragma unroll
        for (int r = 0; r < 4; r++) red[w][hb + r] = sum[r];
    }
    __syncthreads();
    #pragma unroll
    for (int r = 0; r < 4; r++) {
        float inv = 1.0f / (red[0][hb + r] + red[1][hb + r] + red[2][hb + r] + red[3][hb + r]);
        int h = hb + r;
        #pragma unroll
        for (int c = 0; c < 8; c++) {
            int k = kw + c * 16 + lc;
            A_lds[h * 512 + (k ^ ((h & 7) << 3))] = f2bf(vals[c][r] * inv);
        }
    }
    __syncthreads();
    // coalesced global A write from LDS
    {
        int h2 = t >> 4, cbase = (t & 15) * 32;
        #pragma unroll
        for (int j = 0; j < 4; j++) {
            int kidx = cbase + j * 8;
            ushort8 v = *(ushort8*)&A_lds[h2 * 512 + (kidx ^ ((h2 & 7) << 3))];
            *(ushort8*)&s1[h2 * 512 + kidx] = v;
        }
    }

    // ---- phase B: ar = A @ r_v (MFMA; r_v B-frags direct from global, NO barriers)
    f32x4 aacc = {0, 0, 0, 0};
    int h0 = lane & 15;
    const float* rvd = rv + (size_t)((lane >> 4) * 8) * 64 + w * 16 + (lane & 15);
    for (int kc = 0; kc < 16; kc++) {
        int kidx = kc * 32 + (lane >> 4) * 8;
        bf16x8 afr = *(bf16x8*)&A_lds[h0 * 512 + (kidx ^ ((h0 & 7) << 3))];
        const float* p = rvd + (size_t)(kc * 32) * 64;
        float4 y0, y1;
        y0.x = p[0];       y0.y = p[64];      y0.z = p[128];     y0.w = p[192];
        y1.x = p[256];     y1.y = p[320];     y1.z = p[384];     y1.w = p[448];
        aacc = __builtin_amdgcn_mfma_f32_16x16x32_bf16(afr, cvt8p(y0, y1), aacc, 0, 0, 0);
    }
    #pragma unroll
    for (int r = 0; r < 4; r++) ar_s[(lane >> 4) * 4 + r][w * 16 + (lane & 15)] = aacc[r];
    __syncthreads();
    int h = t >> 4, d0 = (t & 15) * 4;
    float4 bb = *(const float4*)&br[d0];
    float o[4] = {bb.x, bb.y, bb.z, bb.w};
    for (int rr = 0; rr < 64; rr++) {
        float a = ar_s[h][rr];
        float4 wr4 = *(const float4*)&Wr[(size_t)rr * DKd + d0];
        o[0] += a * wr4.x; o[1] += a * wr4.y; o[2] += a * wr4.z; o[3] += a * wr4.w;
    }
    float4 ov = {o[0], o[1], o[2], o[3]};
    *(float4*)&ctx2[(size_t)bq * DMd + h * 64 + d0] = ov;
}

// ------------------------------- ctx = A @ V + ctx2 (bf16), batched per (b,h), 2-phase dbuf
__global__ __launch_bounds__(256) void pv_gemm(const ushort_t* __restrict__ A,
                                               const ushort_t* __restrict__ Vt,
                                               const float* __restrict__ ctx2,
                                               ushort_t* __restrict__ ctx) {
    __shared__ ushort_t A_s[2][128 * 64];
    __shared__ ushort_t B_s[2][64 * 64];
    int t = threadIdx.x, lane = t & 63, w = t >> 6;
    int qt = blockIdx.x;
    int bh = blockIdx.y, b = bh >> 4, h = bh & 15;
    int srow = lane >> 3, sp = lane & 7;
    int scol = (sp ^ srow) * 8;
    const ushort_t* Ab = A + ((size_t)(b * 512 + qt * 128) * 16 + h) * 512 + scol;
    const ushort_t* Vb = Vt + (size_t)bh * 64 * 512 + scol;
    int wm0 = (w >> 1) * 64, wn0 = (w & 1) * 32;
    f32x4 acc[4][2] = {};

    #pragma unroll
    for (int i = 0; i < 4; i++) {
        int cc = w * 4 + i;
        gld_lds16(Ab + (size_t)(cc * 8 + srow) * 8192, &A_s[0][cc * 512]);
    }
    {
        int cc = w * 2;
        gld_lds16(Vb + (size_t)(cc * 8 + srow) * 512, &B_s[0][cc * 512]);
        gld_lds16(Vb + (size_t)((cc + 1) * 8 + srow) * 512, &B_s[0][(cc + 1) * 512]);
    }
    __syncthreads();

    for (int kt = 0; kt < 8; kt++) {
        int cur = kt & 1;
        if (kt + 1 < 8) {
            int k0 = (kt + 1) << 6;
            #pragma unroll
            for (int i = 0; i < 4; i++) {
                int cc = w * 4 + i;
                gld_lds16(Ab + (size_t)(cc * 8 + srow) * 8192 + k0, &A_s[cur ^ 1][cc * 512]);
            }
            int cc = w * 2;
            gld_lds16(Vb + (size_t)(cc * 8 + srow) * 512 + k0, &B_s[cur ^ 1][cc * 512]);
            gld_lds16(Vb + (size_t)((cc + 1) * 8 + srow) * 512 + k0, &B_s[cur ^ 1][(cc + 1) * 512]);
        }
        #pragma unroll
        for (int c = 0; c < 2; c++) {
            int q8 = c * 4 + (lane >> 4);
            bf16x8 af[4], bfr[2];
            #pragma unroll
            for (int mi = 0; mi < 4; mi++) {
                int row = wm0 + mi * 16 + (lane & 15);
                af[mi] = *(bf16x8*)&A_s[cur][row * 64 + ((q8 ^ (row & 7)) * 8)];
            }
            #pragma unroll
            for (int ni = 0; ni < 2; ni++) {
                int row = wn0 + ni * 16 + (lane & 15);
                bfr[ni] = *(bf16x8*)&B_s[cur][row * 64 + ((q8 ^ (row & 7)) * 8)];
            }
            #pragma unroll
            for (int mi = 0; mi < 4; mi++)
                #pragma unroll
                for (int ni = 0; ni < 2; ni++)
                    acc[mi][ni] = __builtin_amdgcn_mfma_f32_16x16x32_bf16(af[mi], bfr[ni], acc[mi][ni], 0, 0, 0);
        }
        __syncthreads();
    }
    #pragma unroll
    for (int mi = 0; mi < 4; mi++) {
        #pragma unroll
        for (int ni = 0; ni < 2; ni++) {
            #pragma unroll
            for (int r = 0; r < 4; r++) {
                int qrow = qt * 128 + wm0 + mi * 16 + (lane >> 4) * 4 + r;
                int d = wn0 + ni * 16 + (lane & 15);
                size_t idx = (size_t)(b * 512 + qrow) * DMd + h * 64 + d;
                ctx[idx] = f2bf(acc[mi][ni][r] + ctx2[idx]);
            }
        }
    }
}

// ---------------------------------------------------------------------------
extern "C" void kernel_launch(void* const* d_in, const int* in_sizes, int n_in,
                              void* d_out, int out_size, void* d_ws, size_t ws_size,
                              hipStream_t stream) {
    const float* x   = (const float*)d_in[0];
    const float* r_k = (const float*)d_in[1];
    const float* r_v = (const float*)d_in[2];
    const float* g1 = (const float*)d_in[4];
    const float* b1 = (const float*)d_in[5];
    const float* Wq = (const float*)d_in[6];
    const float* bq = (const float*)d_in[7];
    const float* Wk = (const float*)d_in[8];
    const float* bk = (const float*)d_in[9];
    const float* Wv = (const float*)d_in[10];
    const float* bv = (const float*)d_in[11];
    const float* Wr = (const float*)d_in[12];
    const float* br = (const float*)d_in[13];
    const float* Wo = (const float*)d_in[14];
    const float* bo = (const float*)d_in[15];
    const float* g2 = (const float*)d_in[16];
    const float* b2 = (const float*)d_in[17];
    const float* W1 = (const float*)d_in[18];
    const float* c1 = (const float*)d_in[19];
    const float* W2 = (const float*)d_in[20];
    const float* c2 = (const float*)d_in[21];

    const size_t MB = 1024 * 1024;
    char* w8 = (char*)d_ws;
    ushort_t* qkv   = (ushort_t*)(w8 + 0);              // 16 MB [2048][4096] Q|K|V|QR
    ushort_t* Vt    = (ushort_t*)(w8 + 16 * MB);        // 4 MB
    ushort_t* S1A   = (ushort_t*)(w8 + 20 * MB);        // 32 MB
    ushort_t* hbuf  = (ushort_t*)(w8 + 52 * MB);        // 4 MB (h / ctx / h2)
    float*    out1  = (float*)(w8 + 56 * MB);           // 8 MB
    float*    ctx2  = (float*)(w8 + 64 * MB);           // 8 MB
    float*    qkvb  = (float*)(w8 + 72 * MB);           // 16 KB
    ushort_t* Wqkvt = (ushort_t*)(w8 + 73 * MB);        // 8 MB (Q|K|V|QR weights)
    ushort_t* Wot   = (ushort_t*)(w8 + 81 * MB);        // 2 MB
    ushort_t* W1t   = (ushort_t*)(w8 + 83 * MB);        // 8 MB
    ushort_t* W2t   = (ushort_t*)(w8 + 91 * MB);        // 8 MB
    ushort_t* f1    = (ushort_t*)(w8 + 99 * MB);        // 16 MB
    float*    outp  = (float*)d_out;

    const int ROWS = Bd * Ld;  // 2048
    dim3 blk(256);

    transpose_cast3<<<dim3(32, 32, 3), blk, 0, stream>>>(Wq, Wk, Wv, Wqkvt);
    wqr_kernel<<<dim3(256), blk, 0, stream>>>(Wq, Wr, Wqkvt);
    catbias<<<dim3(16), blk, 0, stream>>>(bq, bk, bv, Wr, qkvb);
    ln_kernel<<<dim3(ROWS), blk, 0, stream>>>(x, g1, b1, hbuf);
    gemm_bf16<0, 1, 128><<<dim3(4096 / 128, ROWS / 128), blk, 0, stream>>>(
        hbuf, Wqkvt, qkvb, nullptr, qkv, ROWS, 4096, 1024);
    vt_kernel<<<dim3(64, 8), blk, 0, stream>>>(qkv, Vt);
    qk_gemm<<<dim3(1024), blk, 0, stream>>>(qkv, S1A);
    scar_kernel<<<dim3(ROWS), blk, 0, stream>>>(qkv, r_k, r_v, Wr, br, S1A, ctx2);
    pv_gemm<<<dim3(4, 64), blk, 0, stream>>>(S1A, Vt, ctx2, hbuf);
    transpose_cast<<<dim3(32, 32), blk, 0, stream>>>(Wo, Wot, 1024, 1024);
    transpose_cast<<<dim3(128, 32), blk, 0, stream>>>(W1, W1t, 1024, 4096);
    transpose_cast<<<dim3(32, 128), blk, 0, stream>>>(W2, W2t, 4096, 1024);
    gemm_bf16<1, 0, 64><<<dim3(1024 / 64, ROWS / 128), blk, 0, stream>>>(
        hbuf, Wot, bo, x, out1, ROWS, 1024, 1024);
    ln_kernel<<<dim3(ROWS), blk, 0, stream>>>(out1, g2, b2, hbuf);
    gemm_bf16<2, 1, 128><<<dim3(4096 / 128, ROWS / 128), blk, 0, stream>>>(
        hbuf, W1t, c1, nullptr, f1, ROWS, 4096, 1024);
    gemm_bf16<1, 0, 64><<<dim3(1024 / 64, ROWS / 128), blk, 0, stream>>>(
        f1, W2t, c2, out1, outp, ROWS, 1024, 4096);
}

// Round 13
// 307.129 us; speedup vs baseline: 1.0040x; 1.0040x over previous
//
#include <hip/hip_runtime.h>

#define Bd 4
#define Ld 512
#define DMd 1024
#define Hd 16
#define DKd 64
#define DRd 64
#define DFd 4096
#define LDN 4096

typedef unsigned short ushort_t;
typedef short bf16x8 __attribute__((ext_vector_type(8)));
typedef float f32x4 __attribute__((ext_vector_type(4)));
typedef unsigned short ushort8 __attribute__((ext_vector_type(8)));

__device__ __forceinline__ float bf2f(ushort_t u) {
    return __uint_as_float(((unsigned int)u) << 16);
}
__device__ __forceinline__ ushort_t f2bf(float x) {
    unsigned int u = __float_as_uint(x);
    unsigned int r = (u + 0x7fffu + ((u >> 16) & 1u)) >> 16;
    return (ushort_t)r;
}
// round-half-up bf16 pair pack: 2 adds + 1 v_perm per 2 elements
__device__ __forceinline__ unsigned int pack2(float a, float b) {
    unsigned int ua = __float_as_uint(a) + 0x8000u;
    unsigned int ub = __float_as_uint(b) + 0x8000u;
    return __builtin_amdgcn_perm(ub, ua, 0x07060302u);
}
__device__ __forceinline__ bf16x8 cvt8p(float4 a, float4 b) {
    union { unsigned int u[4]; bf16x8 v; } r;
    r.u[0] = pack2(a.x, a.y);
    r.u[1] = pack2(a.z, a.w);
    r.u[2] = pack2(b.x, b.y);
    r.u[3] = pack2(b.z, b.w);
    return r.v;
}
__device__ __forceinline__ ushort_t f2bf_hu(float x) {
    return (ushort_t)((__float_as_uint(x) + 0x8000u) >> 16);
}

typedef __attribute__((address_space(3))) void as3_void;
typedef const __attribute__((address_space(1))) void as1_cvoid;
__device__ __forceinline__ void gld_lds16(const ushort_t* g, ushort_t* l) {
    __builtin_amdgcn_global_load_lds((as1_cvoid*)g, (as3_void*)l, 16, 0, 0);
}

// ---------------------------------------------------------------- LayerNorm (fp32 in, bf16 out)
__global__ __launch_bounds__(256) void ln_kernel(const float* __restrict__ x,
                                                 const float* __restrict__ g,
                                                 const float* __restrict__ bta,
                                                 ushort_t* __restrict__ out) {
    __shared__ float red[4];
    int row = blockIdx.x;
    int t = threadIdx.x;
    const float* xr = x + (size_t)row * DMd;
    float4 xv = *(const float4*)(xr + t * 4);
    float s = xv.x + xv.y + xv.z + xv.w;
    #pragma unroll
    for (int off = 32; off; off >>= 1) s += __shfl_down(s, off, 64);
    if ((t & 63) == 0) red[t >> 6] = s;
    __syncthreads();
    float mean = (red[0] + red[1] + red[2] + red[3]) * (1.0f / DMd);
    __syncthreads();
    float dx = xv.x - mean, dy = xv.y - mean, dz = xv.z - mean, dw = xv.w - mean;
    float vs = dx * dx + dy * dy + dz * dz + dw * dw;
    #pragma unroll
    for (int off = 32; off; off >>= 1) vs += __shfl_down(vs, off, 64);
    if ((t & 63) == 0) red[t >> 6] = vs;
    __syncthreads();
    float var = (red[0] + red[1] + red[2] + red[3]) * (1.0f / DMd);
    float inv = rsqrtf(var + 1e-6f);
    float4 gv = *(const float4*)(g + t * 4);
    float4 bv = *(const float4*)(bta + t * 4);
    ushort4 o;
    o.x = f2bf(dx * inv * gv.x + bv.x);
    o.y = f2bf(dy * inv * gv.y + bv.y);
    o.z = f2bf(dz * inv * gv.z + bv.z);
    o.w = f2bf(dw * inv * gv.w + bv.w);
    *(ushort4*)(out + (size_t)row * DMd + t * 4) = o;
}

// -------------------------------------------------- transpose+cast: W[K][N] f32 -> Wt[N][K] bf16
__global__ __launch_bounds__(256) void transpose_cast(const float* __restrict__ W,
                                                      ushort_t* __restrict__ Wt,
                                                      int K, int N) {
    __shared__ float tile[32][33];
    int t = threadIdx.x;
    int n0 = blockIdx.x * 32, k0 = blockIdx.y * 32;
    int r = t >> 3, c4 = (t & 7) * 4;
    float4 w = *(const float4*)&W[(size_t)(k0 + r) * N + n0 + c4];
    tile[r][c4 + 0] = w.x; tile[r][c4 + 1] = w.y;
    tile[r][c4 + 2] = w.z; tile[r][c4 + 3] = w.w;
    __syncthreads();
    int n = t >> 3, k4 = (t & 7) * 4;
    ushort4 o;
    o.x = f2bf(tile[k4 + 0][n]); o.y = f2bf(tile[k4 + 1][n]);
    o.z = f2bf(tile[k4 + 2][n]); o.w = f2bf(tile[k4 + 3][n]);
    *(ushort4*)&Wt[(size_t)(n0 + n) * K + k0 + k4] = o;
}

// ---------------------------- 3 stacked 1024x1024 transposes (Wq/Wk/Wv) in one launch
__global__ __launch_bounds__(256) void transpose_cast3(const float* __restrict__ W0,
                                                       const float* __restrict__ W1p,
                                                       const float* __restrict__ W2p,
                                                       ushort_t* __restrict__ Wt) {
    __shared__ float tile[32][33];
    int z = blockIdx.z;
    const float* W = (z == 0) ? W0 : (z == 1 ? W1p : W2p);
    ushort_t* dst = Wt + (size_t)z * 1024 * 1024;
    int t = threadIdx.x;
    int n0 = blockIdx.x * 32, k0 = blockIdx.y * 32;
    int r = t >> 3, c4 = (t & 7) * 4;
    float4 w = *(const float4*)&W[(size_t)(k0 + r) * 1024 + n0 + c4];
    tile[r][c4 + 0] = w.x; tile[r][c4 + 1] = w.y;
    tile[r][c4 + 2] = w.z; tile[r][c4 + 3] = w.w;
    __syncthreads();
    int n = t >> 3, k4 = (t & 7) * 4;
    ushort4 o;
    o.x = f2bf(tile[k4 + 0][n]); o.y = f2bf(tile[k4 + 1][n]);
    o.z = f2bf(tile[k4 + 2][n]); o.w = f2bf(tile[k4 + 3][n]);
    *(ushort4*)&dst[(size_t)(n0 + n) * 1024 + k0 + k4] = o;
}

// ---------------- Wqrt[3072 + h*64+r][k] = 0.125 * sum_d Wr[r][d] * Wq[k][h*64+d]
__global__ __launch_bounds__(256) void wqr_kernel(const float* __restrict__ Wq,
                                                  const float* __restrict__ Wr,
                                                  ushort_t* __restrict__ Wqkvt) {
    __shared__ float wr_s[64 * 64];
    __shared__ float wq_s[64 * 68];
    int h = blockIdx.x >> 4, kc = blockIdx.x & 15;
    int t = threadIdx.x;
    #pragma unroll
    for (int i = 0; i < 4; i++) {
        int idx = t + i * 256;
        *(float4*)&wr_s[idx * 4] = *(const float4*)&Wr[idx * 4];
        int kk = idx >> 4, d4 = (idx & 15) * 4;
        *(float4*)&wq_s[kk * 68 + d4] =
            *(const float4*)&Wq[(size_t)(kc * 64 + kk) * 1024 + h * 64 + d4];
    }
    __syncthreads();
    int r = t >> 2, kq = t & 3;
    float acc[16] = {};
    for (int d = 0; d < 64; d++) {
        float wr = wr_s[r * 64 + d];
        #pragma unroll
        for (int i = 0; i < 16; i++) acc[i] += wr * wq_s[(kq * 16 + i) * 68 + d];
    }
    ushort8 o0, o1;
    #pragma unroll
    for (int i = 0; i < 8; i++) {
        o0[i] = f2bf(acc[i] * 0.125f);
        o1[i] = f2bf(acc[8 + i] * 0.125f);
    }
    ushort_t* dst = Wqkvt + ((size_t)(3072 + h * 64 + r)) * 1024 + kc * 64 + kq * 16;
    *(ushort8*)dst = o0;
    *(ushort8*)(dst + 8) = o1;
}

// ------------------ qkvb[0..3071] = bq|bk|bv ; qkvb[3072+h*64+r] = 0.125*sum_d bq[h*64+d]Wr[r][d]
__global__ __launch_bounds__(256) void catbias(const float* __restrict__ bq,
                                               const float* __restrict__ bk,
                                               const float* __restrict__ bv,
                                               const float* __restrict__ Wr,
                                               float* __restrict__ o) {
    int i = blockIdx.x * 256 + threadIdx.x;
    float v;
    if (i < 1024) v = bq[i];
    else if (i < 2048) v = bk[i - 1024];
    else if (i < 3072) v = bv[i - 2048];
    else {
        int j = i - 3072, h = j >> 6, r = j & 63;
        float a = 0.0f;
        for (int d = 0; d < 64; d++) a += bq[h * 64 + d] * Wr[r * 64 + d];
        v = a * 0.125f;
    }
    o[i] = v;
}

// ------------------------------------------------- bf16 MFMA GEMM + epilogue (2-phase dbuf)
template <int EPI, int OUTBF16, int BN_>
__global__ __launch_bounds__(256) void gemm_bf16(const ushort_t* __restrict__ A,
                                                 const ushort_t* __restrict__ Bt,
                                                 const float* __restrict__ bias,
                                                 const float* __restrict__ res,
                                                 void* __restrict__ Cout,
                                                 int M, int N, int K) {
    constexpr int NI = BN_ / 32;
    constexpr int NCB = BN_ / 32;
    __shared__ ushort_t A_s[2][128 * 64];
    __shared__ ushort_t B_s[2][BN_ * 64];
    int t = threadIdx.x, lane = t & 63, w = t >> 6;

    int nbx = gridDim.x;
    int flat = blockIdx.y * nbx + blockIdx.x;
    int cpx = (nbx * gridDim.y) >> 3;
    int swz = (flat & 7) * cpx + (flat >> 3);
    int bx = swz % nbx, by = swz / nbx;
    int row0 = by * 128, col0 = bx * BN_;

    int wm0 = (w >> 1) * 64;
    int wn0 = (w & 1) * (BN_ / 2);
    int srow = lane >> 3;
    int sp = lane & 7;
    int scol = (sp ^ srow) * 8;

    const ushort_t* Abase = A + (size_t)row0 * K + scol;
    const ushort_t* Bbase = Bt + (size_t)col0 * K + scol;

    f32x4 acc[4][NI] = {};
    int nt = K >> 6;

    #pragma unroll
    for (int i = 0; i < 4; i++) {
        int cc = w * 4 + i;
        gld_lds16(Abase + (size_t)(cc * 8 + srow) * K, &A_s[0][cc * 512]);
    }
    #pragma unroll
    for (int i = 0; i < NCB; i++) {
        int cc = w * NCB + i;
        gld_lds16(Bbase + (size_t)(cc * 8 + srow) * K, &B_s[0][cc * 512]);
    }
    __syncthreads();

    for (int kt = 0; kt < nt; kt++) {
        int cur = kt & 1;
        if (kt + 1 < nt) {
            int k0 = (kt + 1) << 6;
            #pragma unroll
            for (int i = 0; i < 4; i++) {
                int cc = w * 4 + i;
                gld_lds16(Abase + (size_t)(cc * 8 + srow) * K + k0, &A_s[cur ^ 1][cc * 512]);
            }
            #pragma unroll
            for (int i = 0; i < NCB; i++) {
                int cc = w * NCB + i;
                gld_lds16(Bbase + (size_t)(cc * 8 + srow) * K + k0, &B_s[cur ^ 1][cc * 512]);
            }
        }
        #pragma unroll
        for (int c = 0; c < 2; c++) {
            int q8 = c * 4 + (lane >> 4);
            bf16x8 af[4], bfr[NI];
            #pragma unroll
            for (int mi = 0; mi < 4; mi++) {
                int row = wm0 + mi * 16 + (lane & 15);
                af[mi] = *(bf16x8*)&A_s[cur][row * 64 + ((q8 ^ (row & 7)) * 8)];
            }
            #pragma unroll
            for (int ni = 0; ni < NI; ni++) {
                int row = wn0 + ni * 16 + (lane & 15);
                bfr[ni] = *(bf16x8*)&B_s[cur][row * 64 + ((q8 ^ (row & 7)) * 8)];
            }
            #pragma unroll
            for (int mi = 0; mi < 4; mi++)
                #pragma unroll
                for (int ni = 0; ni < NI; ni++)
                    acc[mi][ni] = __builtin_amdgcn_mfma_f32_16x16x32_bf16(af[mi], bfr[ni], acc[mi][ni], 0, 0, 0);
        }
        __syncthreads();
    }
    #pragma unroll
    for (int mi = 0; mi < 4; mi++) {
        #pragma unroll
        for (int ni = 0; ni < NI; ni++) {
            int col = col0 + wn0 + ni * 16 + (lane & 15);
            float bcol = bias[col];
            #pragma unroll
            for (int r = 0; r < 4; r++) {
                int row = row0 + wm0 + mi * 16 + (lane >> 4) * 4 + r;
                float v = acc[mi][ni][r] + bcol;
                if (EPI == 1) v += res[(size_t)row * N + col];
                if (EPI == 2) v = fmaxf(v, 0.0f);
                if (OUTBF16) ((ushort_t*)Cout)[(size_t)row * N + col] = f2bf(v);
                else         ((float*)Cout)[(size_t)row * N + col] = v;
            }
        }
    }
}

// ----------------------------------------- S1 = Q.K^T * 0.125 (bf16), batched per (b,h)
__global__ __launch_bounds__(256) void qk_gemm(const ushort_t* __restrict__ qkv,
                                               ushort_t* __restrict__ S1) {
    __shared__ ushort_t Q_s[128 * 64];
    __shared__ ushort_t K_s[128 * 64];
    int t = threadIdx.x, lane = t & 63, w = t >> 6;
    int qt = blockIdx.x & 3, kt = (blockIdx.x >> 2) & 3, bh = blockIdx.x >> 4;
    int b = bh >> 4, h = bh & 15;
    const ushort_t* Qb = qkv + (size_t)(b * 512 + qt * 128) * LDN + h * 64;
    const ushort_t* Kb = qkv + (size_t)(b * 512 + kt * 128) * LDN + 1024 + h * 64;
    #pragma unroll
    for (int i = 0; i < 4; i++) {
        int cc = w + 4 * i;
        int flat = cc * 64 + lane;
        int row = flat >> 3, p = flat & 7;
        int srcoff = ((p ^ (row & 7)) * 8);
        gld_lds16(Qb + (size_t)row * LDN + srcoff, &Q_s[cc * 512]);
        gld_lds16(Kb + (size_t)row * LDN + srcoff, &K_s[cc * 512]);
    }
    __syncthreads();
    int wm0 = (w >> 1) * 64, wn0 = (w & 1) * 64;
    f32x4 acc[4][4] = {};
    #pragma unroll
    for (int c = 0; c < 2; c++) {
        int q8 = c * 4 + (lane >> 4);
        bf16x8 af[4], bfr[4];
        #pragma unroll
        for (int mi = 0; mi < 4; mi++) {
            int row = wm0 + mi * 16 + (lane & 15);
            af[mi] = *(bf16x8*)&Q_s[row * 64 + ((q8 ^ (row & 7)) * 8)];
        }
        #pragma unroll
        for (int ni = 0; ni < 4; ni++) {
            int row = wn0 + ni * 16 + (lane & 15);
            bfr[ni] = *(bf16x8*)&K_s[row * 64 + ((q8 ^ (row & 7)) * 8)];
        }
        #pragma unroll
        for (int mi = 0; mi < 4; mi++)
            #pragma unroll
            for (int ni = 0; ni < 4; ni++)
                acc[mi][ni] = __builtin_amdgcn_mfma_f32_16x16x32_bf16(af[mi], bfr[ni], acc[mi][ni], 0, 0, 0);
    }
    #pragma unroll
    for (int mi = 0; mi < 4; mi++) {
        #pragma unroll
        for (int ni = 0; ni < 4; ni++) {
            #pragma unroll
            for (int r = 0; r < 4; r++) {
                int qrow = qt * 128 + wm0 + mi * 16 + (lane >> 4) * 4 + r;
                int kcol = kt * 128 + wn0 + ni * 16 + (lane & 15);
                S1[((size_t)(b * 512 + qrow) * 16 + h) * 512 + kcol] = f2bf(acc[mi][ni][r] * 0.125f);
            }
        }
    }
}

// ---------------------------------------------------- Vt[b][h][d][k] = V[b][k][h*64+d]
__global__ __launch_bounds__(256) void vt_kernel(const ushort_t* __restrict__ qkv,
                                                 ushort_t* __restrict__ Vt) {
    __shared__ float tile[64][65];
    int t = threadIdx.x;
    int bh = blockIdx.x, b = bh >> 4, h = bh & 15;
    int kt = blockIdx.y;
    const ushort_t* src = qkv + (size_t)b * 512 * LDN + 2048 + h * 64;
    ushort_t* dst = Vt + (size_t)bh * 64 * 512;
    #pragma unroll
    for (int i = 0; i < 2; i++) {
        int item = t + i * 256;
        int kk = item >> 3, d8 = (item & 7) * 8;
        ushort8 v = *(const ushort8*)(src + (size_t)(kt * 64 + kk) * LDN + d8);
        #pragma unroll
        for (int j = 0; j < 8; j++) tile[kk][d8 + j] = bf2f(v[j]);
    }
    __syncthreads();
    #pragma unroll
    for (int i = 0; i < 2; i++) {
        int item = t + i * 256;
        int d = item >> 3, kc = (item & 7) * 8;
        ushort8 o;
        #pragma unroll
        for (int j = 0; j < 8; j++) o[j] = f2bf(tile[kc + j][d]);
        *(ushort8*)(dst + (size_t)d * 512 + kt * 64 + kc) = o;
    }
}

// ------------ fused: scores = S1 + qr.r_k^T -> softmax -> A ; ctx2 = (A@r_v)@Wr + br
//              phase A: per-wave private LDS chunks, NO barriers in K loop, 2-deep reg prefetch
//              phase B: direct-global r_v B-fragments (barrier-free)
__global__ __launch_bounds__(256, 4) void scar_kernel(const ushort_t* __restrict__ qkv,
                                                      const float* __restrict__ r_k,
                                                      const float* __restrict__ r_v,
                                                      const float* __restrict__ Wr,
                                                      const float* __restrict__ br,
                                                      ushort_t* __restrict__ S1A,
                                                      float* __restrict__ ctx2) {
    __shared__ float red[4][16];
    __shared__ ushort_t A_lds[16 * 512];     // 16 KB, XOR-swizzled [h][k]
    __shared__ ushort_t st[4][2][16 * 64];   // 16 KB: per-wave dbuf chunks [16k][64d]
    __shared__ float ar_s[16][68];
    int t = threadIdx.x, lane = t & 63, w = t >> 6;
    int bq = blockIdx.x;
    const ushort_t* qr = qkv + (size_t)bq * LDN + 3072;
    const float* rk = r_k + (size_t)bq * 512 * 64;
    const float* rv = r_v + (size_t)bq * 512 * 64;
    ushort_t* s1 = S1A + (size_t)bq * 16 * 512;

    // A-fragments of qr (per-head 16x64)
    bf16x8 af0 = *(const bf16x8*)&qr[(lane & 15) * 64 + (lane >> 4) * 8];
    bf16x8 af1 = *(const bf16x8*)&qr[(lane & 15) * 64 + 32 + (lane >> 4) * 8];

    // ---- phase A: wave w owns k-rows [w*128, w*128+128) = 8 chunks of 16
    int kw = w * 128;
    int lr = lane >> 4;              // 0..3
    int lc = lane & 15;              // d-col group (d0 = lc*4)
    int dg = (lane >> 1) & 7;        // (lc*4)>>3
    int dlo = (lane & 1) * 4;        // (lc*4)&7
    const float* rkb = rk + (size_t)(kw + lr) * 64 + lc * 4;

    float4 ra[4], rb[4];
    #pragma unroll
    for (int i = 0; i < 4; i++) ra[i] = *(const float4*)(rkb + (size_t)(i * 4) * 64);
    #pragma unroll
    for (int i = 0; i < 4; i++) rb[i] = *(const float4*)(rkb + (size_t)(16 + i * 4) * 64);

    f32x4 acc[8] = {};
    #pragma unroll
    for (int c = 0; c < 8; c++) {
        ushort_t* sb = &st[w][c & 1][0];
        #pragma unroll
        for (int i = 0; i < 4; i++) {
            float4 v = (c & 1) ? rb[i] : ra[i];
            int kl = i * 4 + lr;
            ushort4 o;
            o.x = f2bf_hu(v.x); o.y = f2bf_hu(v.y);
            o.z = f2bf_hu(v.z); o.w = f2bf_hu(v.w);
            *(ushort4*)&sb[kl * 64 + ((dg ^ (kl & 7)) * 8) + dlo] = o;
        }
        if (c + 2 < 8) {
            #pragma unroll
            for (int i = 0; i < 4; i++) {
                float4 v = *(const float4*)(rkb + (size_t)((c + 2) * 16 + i * 4) * 64);
                if (c & 1) rb[i] = v; else ra[i] = v;
            }
        }
        #pragma unroll
        for (int hf = 0; hf < 2; hf++) {
            int u = lc * 64 + (((hf * 4 + lr) ^ (lc & 7)) * 8);
            bf16x8 bfr = *(bf16x8*)&sb[u];
            acc[c] = __builtin_amdgcn_mfma_f32_16x16x32_bf16(hf ? af1 : af0, bfr, acc[c], 0, 0, 0);
        }
    }

    // ---- softmax (k = kw + c*16 + lc, h = lr*4 + r)
    int hb = lr * 4;
    float vals[8][4];
    #pragma unroll
    for (int c = 0; c < 8; c++)
        #pragma unroll
        for (int r = 0; r < 4; r++)
            vals[c][r] = acc[c][r] + bf2f(s1[(hb + r) * 512 + kw + c * 16 + lc]);

    float m[4];
    #pragma unroll
    for (int r = 0; r < 4; r++) {
        m[r] = vals[0][r];
        #pragma unroll
        for (int c = 1; c < 8; c++) m[r] = fmaxf(m[r], vals[c][r]);
        #pragma unroll
        for (int msk = 1; msk < 16; msk <<= 1) m[r] = fmaxf(m[r], __shfl_xor(m[r], msk, 64));
    }
    if (lc == 0) {
        #pragma unroll
        for (int r = 0; r < 4; r++) red[w][hb + r] = m[r];
    }
    __syncthreads();
    float sum[4];
    #pragma unroll
    for (int r = 0; r < 4; r++) {
        float mg = fmaxf(fmaxf(red[0][hb + r], red[1][hb + r]),
                         fmaxf(red[2][hb + r], red[3][hb + r]));
        float s = 0.0f;
        #pragma unroll
        for (int c = 0; c < 8; c++) {
            float e = __expf(vals[c][r] - mg);
            vals[c][r] = e;
            s += e;
        }
        #pragma unroll
        for (int msk = 1; msk < 16; msk <<= 1) s += __shfl_xor(s, msk, 64);
        sum[r] = s;
    }
    __syncthreads();
    if (lc == 0) {
        #pragma unroll
        for (int r = 0; r < 4; r++) red[w][hb + r] = sum[r];
    }
    __syncthreads();
    #pragma unroll
    for (int r = 0; r < 4; r++) {
        float inv = 1.0f / (red[0][hb + r] + red[1][hb + r] + red[2][hb + r] + red[3][hb + r]);
        int h = hb + r;
        #pragma unroll
        for (int c = 0; c < 8; c++) {
            int k = kw + c * 16 + lc;
            A_lds[h * 512 + (k ^ ((h & 7) << 3))] = f2bf(vals[c][r] * inv);
        }
    }
    __syncthreads();
    // coalesced global A write from LDS
    {
        int h2 = t >> 4, cbase = (t & 15) * 32;
        #pragma unroll
        for (int j = 0; j < 4; j++) {
            int kidx = cbase + j * 8;
            ushort8 v = *(ushort8*)&A_lds[h2 * 512 + (kidx ^ ((h2 & 7) << 3))];
            *(ushort8*)&s1[h2 * 512 + kidx] = v;
        }
    }

    // ---- phase B: ar = A @ r_v (MFMA; r_v B-frags direct from global, NO barriers)
    f32x4 aacc = {0, 0, 0, 0};
    int h0 = lane & 15;
    const float* rvd = rv + (size_t)((lane >> 4) * 8) * 64 + w * 16 + (lane & 15);
    for (int kc = 0; kc < 16; kc++) {
        int kidx = kc * 32 + (lane >> 4) * 8;
        bf16x8 afr = *(bf16x8*)&A_lds[h0 * 512 + (kidx ^ ((h0 & 7) << 3))];
        const float* p = rvd + (size_t)(kc * 32) * 64;
        float4 y0, y1;
        y0.x = p[0];       y0.y = p[64];      y0.z = p[128];     y0.w = p[192];
        y1.x = p[256];     y1.y = p[320];     y1.z = p[384];     y1.w = p[448];
        aacc = __builtin_amdgcn_mfma_f32_16x16x32_bf16(afr, cvt8p(y0, y1), aacc, 0, 0, 0);
    }
    #pragma unroll
    for (int r = 0; r < 4; r++) ar_s[(lane >> 4) * 4 + r][w * 16 + (lane & 15)] = aacc[r];
    __syncthreads();
    int h = t >> 4, d0 = (t & 15) * 4;
    float4 bb = *(const float4*)&br[d0];
    float o[4] = {bb.x, bb.y, bb.z, bb.w};
    for (int rr = 0; rr < 64; rr++) {
        float a = ar_s[h][rr];
        float4 wr4 = *(const float4*)&Wr[(size_t)rr * DKd + d0];
        o[0] += a * wr4.x; o[1] += a * wr4.y; o[2] += a * wr4.z; o[3] += a * wr4.w;
    }
    float4 ov = {o[0], o[1], o[2], o[3]};
    *(float4*)&ctx2[(size_t)bq * DMd + h * 64 + d0] = ov;
}

// ------------------------------- ctx = A @ V + ctx2 (bf16), batched per (b,h), 2-phase dbuf
__global__ __launch_bounds__(256) void pv_gemm(const ushort_t* __restrict__ A,
                                               const ushort_t* __restrict__ Vt,
                                               const float* __restrict__ ctx2,
                                               ushort_t* __restrict__ ctx) {
    __shared__ ushort_t A_s[2][128 * 64];
    __shared__ ushort_t B_s[2][64 * 64];
    int t = threadIdx.x, lane = t & 63, w = t >> 6;
    int qt = blockIdx.x;
    int bh = blockIdx.y, b = bh >> 4, h = bh & 15;
    int srow = lane >> 3, sp = lane & 7;
    int scol = (sp ^ srow) * 8;
    const ushort_t* Ab = A + ((size_t)(b * 512 + qt * 128) * 16 + h) * 512 + scol;
    const ushort_t* Vb = Vt + (size_t)bh * 64 * 512 + scol;
    int wm0 = (w >> 1) * 64, wn0 = (w & 1) * 32;
    f32x4 acc[4][2] = {};

    #pragma unroll
    for (int i = 0; i < 4; i++) {
        int cc = w * 4 + i;
        gld_lds16(Ab + (size_t)(cc * 8 + srow) * 8192, &A_s[0][cc * 512]);
    }
    {
        int cc = w * 2;
        gld_lds16(Vb + (size_t)(cc * 8 + srow) * 512, &B_s[0][cc * 512]);
        gld_lds16(Vb + (size_t)((cc + 1) * 8 + srow) * 512, &B_s[0][(cc + 1) * 512]);
    }
    __syncthreads();

    for (int kt = 0; kt < 8; kt++) {
        int cur = kt & 1;
        if (kt + 1 < 8) {
            int k0 = (kt + 1) << 6;
            #pragma unroll
            for (int i = 0; i < 4; i++) {
                int cc = w * 4 + i;
                gld_lds16(Ab + (size_t)(cc * 8 + srow) * 8192 + k0, &A_s[cur ^ 1][cc * 512]);
            }
            int cc = w * 2;
            gld_lds16(Vb + (size_t)(cc * 8 + srow) * 512 + k0, &B_s[cur ^ 1][cc * 512]);
            gld_lds16(Vb + (size_t)((cc + 1) * 8 + srow) * 512 + k0, &B_s[cur ^ 1][(cc + 1) * 512]);
        }
        #pragma unroll
        for (int c = 0; c < 2; c++) {
            int q8 = c * 4 + (lane >> 4);
            bf16x8 af[4], bfr[2];
            #pragma unroll
            for (int mi = 0; mi < 4; mi++) {
                int row = wm0 + mi * 16 + (lane & 15);
                af[mi] = *(bf16x8*)&A_s[cur][row * 64 + ((q8 ^ (row & 7)) * 8)];
            }
            #pragma unroll
            for (int ni = 0; ni < 2; ni++) {
                int row = wn0 + ni * 16 + (lane & 15);
                bfr[ni] = *(bf16x8*)&B_s[cur][row * 64 + ((q8 ^ (row & 7)) * 8)];
            }
            #pragma unroll
            for (int mi = 0; mi < 4; mi++)
                #pragma unroll
                for (int ni = 0; ni < 2; ni++)
                    acc[mi][ni] = __builtin_amdgcn_mfma_f32_16x16x32_bf16(af[mi], bfr[ni], acc[mi][ni], 0, 0, 0);
        }
        __syncthreads();
    }
    #pragma unroll
    for (int mi = 0; mi < 4; mi++) {
        #pragma unroll
        for (int ni = 0; ni < 2; ni++) {
            #pragma unroll
            for (int r = 0; r < 4; r++) {
                int qrow = qt * 128 + wm0 + mi * 16 + (lane >> 4) * 4 + r;
                int d = wn0 + ni * 16 + (lane & 15);
                size_t idx = (size_t)(b * 512 + qrow) * DMd + h * 64 + d;
                ctx[idx] = f2bf(acc[mi][ni][r] + ctx2[idx]);
            }
        }
    }
}

// ---------------------------------------------------------------------------
extern "C" void kernel_launch(void* const* d_in, const int* in_sizes, int n_in,
                              void* d_out, int out_size, void* d_ws, size_t ws_size,
                              hipStream_t stream) {
    const float* x   = (const float*)d_in[0];
    const float* r_k = (const float*)d_in[1];
    const float* r_v = (const float*)d_in[2];
    const float* g1 = (const float*)d_in[4];
    const float* b1 = (const float*)d_in[5];
    const float* Wq = (const float*)d_in[6];
    const float* bq = (const float*)d_in[7];
    const float* Wk = (const float*)d_in[8];
    const float* bk = (const float*)d_in[9];
    const float* Wv = (const float*)d_in[10];
    const float* bv = (const float*)d_in[11];
    const float* Wr = (const float*)d_in[12];
    const float* br = (const float*)d_in[13];
    const float* Wo = (const float*)d_in[14];
    const float* bo = (const float*)d_in[15];
    const float* g2 = (const float*)d_in[16];
    const float* b2 = (const float*)d_in[17];
    const float* W1 = (const float*)d_in[18];
    const float* c1 = (const float*)d_in[19];
    const float* W2 = (const float*)d_in[20];
    const float* c2 = (const float*)d_in[21];

    const size_t MB = 1024 * 1024;
    char* w8 = (char*)d_ws;
    ushort_t* qkv   = (ushort_t*)(w8 + 0);              // 16 MB [2048][4096] Q|K|V|QR
    ushort_t* Vt    = (ushort_t*)(w8 + 16 * MB);        // 4 MB
    ushort_t* S1A   = (ushort_t*)(w8 + 20 * MB);        // 32 MB
    ushort_t* hbuf  = (ushort_t*)(w8 + 52 * MB);        // 4 MB (h / ctx / h2)
    float*    out1  = (float*)(w8 + 56 * MB);           // 8 MB
    float*    ctx2  = (float*)(w8 + 64 * MB);           // 8 MB
    float*    qkvb  = (float*)(w8 + 72 * MB);           // 16 KB
    ushort_t* Wqkvt = (ushort_t*)(w8 + 73 * MB);        // 8 MB (Q|K|V|QR weights)
    ushort_t* Wot   = (ushort_t*)(w8 + 81 * MB);        // 2 MB
    ushort_t* W1t   = (ushort_t*)(w8 + 83 * MB);        // 8 MB
    ushort_t* W2t   = (ushort_t*)(w8 + 91 * MB);        // 8 MB
    ushort_t* f1    = (ushort_t*)(w8 + 99 * MB);        // 16 MB
    float*    outp  = (float*)d_out;

    const int ROWS = Bd * Ld;  // 2048
    dim3 blk(256);

    transpose_cast3<<<dim3(32, 32, 3), blk, 0, stream>>>(Wq, Wk, Wv, Wqkvt);
    wqr_kernel<<<dim3(256), blk, 0, stream>>>(Wq, Wr, Wqkvt);
    catbias<<<dim3(16), blk, 0, stream>>>(bq, bk, bv, Wr, qkvb);
    ln_kernel<<<dim3(ROWS), blk, 0, stream>>>(x, g1, b1, hbuf);
    gemm_bf16<0, 1, 128><<<dim3(4096 / 128, ROWS / 128), blk, 0, stream>>>(
        hbuf, Wqkvt, qkvb, nullptr, qkv, ROWS, 4096, 1024);
    vt_kernel<<<dim3(64, 8), blk, 0, stream>>>(qkv, Vt);
    qk_gemm<<<dim3(1024), blk, 0, stream>>>(qkv, S1A);
    scar_kernel<<<dim3(ROWS), blk, 0, stream>>>(qkv, r_k, r_v, Wr, br, S1A, ctx2);
    pv_gemm<<<dim3(4, 64), blk, 0, stream>>>(S1A, Vt, ctx2, hbuf);
    transpose_cast<<<dim3(32, 32), blk, 0, stream>>>(Wo, Wot, 1024, 1024);
    transpose_cast<<<dim3(128, 32), blk, 0, stream>>>(W1, W1t, 1024, 4096);
    transpose_cast<<<dim3(32, 128), blk, 0, stream>>>(W2, W2t, 4096, 1024);
    gemm_bf16<1, 0, 64><<<dim3(1024 / 64, ROWS / 128), blk, 0, stream>>>(
        hbuf, Wot, bo, x, out1, ROWS, 1024, 1024);
    ln_kernel<<<dim3(ROWS), blk, 0, stream>>>(out1, g2, b2, hbuf);
    gemm_bf16<2, 1, 128><<<dim3(4096 / 128, ROWS / 128), blk, 0, stream>>>(
        hbuf, W1t, c1, nullptr, f1, ROWS, 4096, 1024);
    gemm_bf16<1, 0, 64><<<dim3(1024 / 64, ROWS / 128), blk, 0, stream>>>(
        f1, W2t, c2, out1, outp, ROWS, 1024, 4096);
}